// Round 18
// baseline (32.229 us; speedup 1.0000x reference)
//
#include <hip/hip_runtime.h>

#define NJ     62
#define NV     14522
#define NCORE  28
#define KPAD   256    // 62*4 = 248 padded to 256 (512 B per row)
#define OUTF   (NV * 3)        // 43566
#define MT     908             // m-tiles of 16 rows
#define NSTR   192             // stripes: 140 of 5 tiles, 52 of 4

typedef __attribute__((ext_vector_type(8))) short short8v;
typedef __attribute__((ext_vector_type(4))) short short4v;
typedef __attribute__((ext_vector_type(4))) float floatx4;
typedef __attribute__((ext_vector_type(2))) float floatx2;

static __device__ inline short f2bf(float x) {
    unsigned u = __float_as_uint(x);
    unsigned r = (u + 0x7fffu + ((u >> 16) & 1u)) >> 16;
    return (short)r;
}

// pack 8 floats -> 8 bf16 (RNE) via v_cvt_pk_bf16_f32
static __device__ inline short8v pack8(float a0, float a1, float a2, float a3,
                                       float a4, float a5, float a6, float a7) {
    union { unsigned u[4]; short8v v; } p;
    asm("v_cvt_pk_bf16_f32 %0, %1, %2" : "=v"(p.u[0]) : "v"(a0), "v"(a1));
    asm("v_cvt_pk_bf16_f32 %0, %1, %2" : "=v"(p.u[1]) : "v"(a2), "v"(a3));
    asm("v_cvt_pk_bf16_f32 %0, %1, %2" : "=v"(p.u[2]) : "v"(a4), "v"(a5));
    asm("v_cvt_pk_bf16_f32 %0, %1, %2" : "=v"(p.u[3]) : "v"(a6), "v"(a7));
    return p.v;
}

// ---------------------------------------------------------------------------
// Kernel 1: forward kinematics. 64 blocks x 256 thr; wave w = batch
// blockIdx*4+w. Writes Jout (fp32) and Bt (bf16) in the PERMUTED K layout:
//   joint j, comps m=0..3 at K-pos q = 32*((j%16)/2) + 8*(j/16) + 4*(j%2) + m
// (matches the gemm's per-lane-contiguous W mapping). Unchanged from r17.
// ---------------------------------------------------------------------------
__global__ __launch_bounds__(256) void fk_kernel(
    const float* __restrict__ thetas, const float* __restrict__ blc,
    const float* __restrict__ cbl, const float* __restrict__ trans,
    const float* __restrict__ scale, const float* __restrict__ tpose,
    const int* __restrict__ parents, const int* __restrict__ mapper,
    short* __restrict__ Bt, float* __restrict__ Jout)
{
    __shared__ float Asm[4][NJ][12];
    __shared__ float Gsm[4][NJ][12];

    const int w = threadIdx.x >> 6;
    const int b = blockIdx.x * 4 + w;
    const int k = threadIdx.x & 63;
    int p = 0;

    if (k < NJ) {
        p = parents[k];
        const float tz = thetas[(b * NJ + k) * 3 + 0];
        const float ty = thetas[(b * NJ + k) * 3 + 1];
        const float tx = thetas[(b * NJ + k) * 3 + 2];
        const float cx = cosf(tx), sx = sinf(tx);
        const float cy = cosf(ty), sy = sinf(ty);
        const float cz = cosf(tz), sz = sinf(tz);
        const float r00 = cz * cy;
        const float r01 = cz * sy * sx - sz * cx;
        const float r02 = sz * sx + cz * sy * cx;
        const float r10 = sz * cy;
        const float r11 = cz * cx + sz * sy * sx;
        const float r12 = sz * sy * cx - cz * sx;
        const float r20 = -sy;
        const float r21 = cy * sx;
        const float r22 = cy * cx;

        float f;
        const int m = mapper[k];
        if (k == 0)        f = 1.0f;
        else if (k == 1)   f = cbl[b];
        else if (m < 0)    f = 1.0f;
        else               f = 2.0f / (1.0f + expf(-blc[b * NCORE + m] * 0.2f));

        float ox, oy, oz;
        if (k == 0) {
            ox = tpose[0]; oy = tpose[1]; oz = tpose[2];
        } else {
            ox = (tpose[k * 3 + 0] - tpose[p * 3 + 0]) * f;
            oy = (tpose[k * 3 + 1] - tpose[p * 3 + 1]) * f;
            oz = (tpose[k * 3 + 2] - tpose[p * 3 + 2]) * f;
        }
        Asm[w][k][0] = r00; Asm[w][k][1] = r01; Asm[w][k][2]  = r02; Asm[w][k][3]  = ox;
        Asm[w][k][4] = r10; Asm[w][k][5] = r11; Asm[w][k][6]  = r12; Asm[w][k][7]  = oy;
        Asm[w][k][8] = r20; Asm[w][k][9] = r21; Asm[w][k][10] = r22; Asm[w][k][11] = oz;
    }
    __syncthreads();

    if (k == 0) {
        #pragma unroll
        for (int j = 0; j < 12; ++j) Gsm[w][0][j] = Asm[w][0][j];
    }
    __syncthreads();

    const int depth = (k < NJ) ? (31 - __clz((unsigned)(k + 1))) : 99;
    for (int d = 1; d <= 5; ++d) {
        if (depth == d) {
            float gp[12], a[12], g[12];
            #pragma unroll
            for (int j = 0; j < 12; ++j) { gp[j] = Gsm[w][p][j]; a[j] = Asm[w][k][j]; }
            #pragma unroll
            for (int i = 0; i < 3; ++i) {
                #pragma unroll
                for (int j = 0; j < 4; ++j) {
                    float s = (j == 3) ? gp[i * 4 + 3] : 0.0f;
                    s = fmaf(gp[i * 4 + 0], a[0 * 4 + j], s);
                    s = fmaf(gp[i * 4 + 1], a[1 * 4 + j], s);
                    s = fmaf(gp[i * 4 + 2], a[2 * 4 + j], s);
                    g[i * 4 + j] = s;
                }
            }
            #pragma unroll
            for (int j = 0; j < 12; ++j) Gsm[w][k][j] = g[j];
        }
        __syncthreads();
    }

    if (k < NJ) {
        float g[12];
        #pragma unroll
        for (int j = 0; j < 12; ++j) g[j] = Gsm[w][k][j];
        const float jx = tpose[k * 3 + 0];
        const float jy = tpose[k * 3 + 1];
        const float jz = tpose[k * 3 + 2];
        const float s  = scale[b];
        Jout[(b * NJ + k) * 3 + 0] = fmaf(g[3],  s, trans[b * 3 + 0]);
        Jout[(b * NJ + k) * 3 + 1] = fmaf(g[7],  s, trans[b * 3 + 1]);
        Jout[(b * NJ + k) * 3 + 2] = fmaf(g[11], s, trans[b * 3 + 2]);
        float np[3];
        np[0] = g[3]  - (g[0] * jx + g[1] * jy + g[2]  * jz);
        np[1] = g[7]  - (g[4] * jx + g[5] * jy + g[6]  * jz);
        np[2] = g[11] - (g[8] * jx + g[9] * jy + g[10] * jz);

        // permuted K position for this joint
        const int lkj = k >> 4;          // j / 16
        const int rr  = k & 15;
        const int qb  = 32 * (rr >> 1) + 8 * lkj + 4 * (rr & 1);
        #pragma unroll
        for (int i = 0; i < 3; ++i) {
            short4v o;
            o[0] = f2bf(g[i * 4 + 0]);
            o[1] = f2bf(g[i * 4 + 1]);
            o[2] = f2bf(g[i * 4 + 2]);
            o[3] = f2bf(np[i]);
            *(short4v*)&Bt[(size_t)(b * 3 + i) * KPAD + qb] = o;
        }
        if (k == 0) {   // zero K padding (joints 62,63 -> q 248..255)
            short4v z = {0, 0, 0, 0};
            #pragma unroll
            for (int i = 0; i < 3; ++i) {
                *(short4v*)&Bt[(size_t)(b * 3 + i) * KPAD + 248] = z;
                *(short4v*)&Bt[(size_t)(b * 3 + i) * KPAD + 252] = z;
            }
        }
    }
}

// ---------------------------------------------------------------------------
// Kernel 2: GEMM + epilogue — r17's coalesced-W kernel with B MOVED TO
// REGISTERS at 3 waves/SIMD (the r9-vs-r12 fork resolved both ways at once):
//  - breg[3][8] (96 VGPR) loaded once straight from global Bt (L2-hot;
//    permuted layout is linear-transparent). No LDS B slab, no swizzle,
//    NO barriers anywhere in the kernel.
//  - per-tile LDS-pipe cost drops ~400 -> ~110 cy (epi transpose only).
//  - no W prefetch (VGPR budget: breg 96 + wc 16 + acc 12 + misc ~35
//    = ~158 <= 168 cap of launch_bounds(256,3)).
// Grid 768 (3 blocks/CU), 192 stripes x 16 y-groups; LDS = 12.8 KB epi.
// ---------------------------------------------------------------------------
__global__ __launch_bounds__(256, 3) void gemm_skin(
    const float* __restrict__ W,      // (V, 62) fp32
    const float* __restrict__ vt,     // (V, 3)  fp32
    const short* __restrict__ Bt,     // (768, KPAD) bf16, permuted K
    const float* __restrict__ scale,  // (B,)
    const float* __restrict__ trans,  // (B*3,)
    float* __restrict__ out)          // (B, V, 3)
{
    __shared__ __align__(16) float epi_all[4 * 800];    // 12.8 KB epi only

    const int tid  = threadIdx.x;
    const int wave = tid >> 6;
    const int lane = tid & 63;
    const int lrow = lane & 15;
    const int lk   = lane >> 4;
    const int yy    = blockIdx.x / 48;          // 0..15 (y-group)
    const int inner = blockIdx.x - yy * 48;     // 0..47
    const int s     = inner * 4 + wave;         // stripe 0..191
    const int start  = s * 4 + (s < 140 ? s : 140);
    const int ntiles = 4 + (s < 140 ? 1 : 0);   // 140*5 + 52*4 = 908
    const int b0 = yy * 16;
    float* epi = epi_all + wave * 800;          // 16 regions x 50 floats

    // ---- B slab -> registers, straight from global (L2-hot, loaded once)
    short8v breg[3][8];
    {
        const short* Bw = Bt + (size_t)yy * 48 * KPAD;
        #pragma unroll
        for (int nt = 0; nt < 3; ++nt)
            #pragma unroll
            for (int k8 = 0; k8 < 8; ++k8)
                breg[nt][k8] = *(const short8v*)(Bw + (nt * 16 + lrow) * KPAD
                                                 + (k8 * 4 + lk) * 8);
    }

    // ---- per-thread invariants
    float sv[3], tv[3]; int eoff[3];
    #pragma unroll
    for (int nt = 0; nt < 3; ++nt) {
        const int n_loc = nt * 16 + lrow;
        const int bl = n_loc / 3, ii = n_loc - bl * 3;
        eoff[nt] = bl * 50 + ii;
        sv[nt] = scale[b0 + bl];
        tv[nt] = trans[(b0 + bl) * 3 + ii];
    }

    for (int t = 0; t < ntiles; ++t) {
        const int mtile = start + t;
        int vrow = mtile * 16 + lrow;
        if (vrow > NV - 1) vrow = NV - 1;           // pad rows: never stored

        // ---- coalesced W gather: 16 contiguous weights at W[row]+16*lk
        //      (4 full-line float4) + vt row
        const float* Wb = W + (size_t)vrow * NJ + lk * 16;
        floatx4 wc[4];
        wc[0] = *(const floatx4*)(Wb + 0);
        wc[1] = *(const floatx4*)(Wb + 4);
        wc[2] = *(const floatx4*)(Wb + 8);
        wc[3] = *(const floatx4*)(Wb + 12);
        const float hx = vt[vrow * 3 + 0];
        const float hy = vt[vrow * 3 + 1];
        const float hz = vt[vrow * 3 + 2];

        // ---- MFMA entirely from registers
        floatx4 acc[3];
        #pragma unroll
        for (int nt = 0; nt < 3; ++nt) acc[nt] = (floatx4){0.f, 0.f, 0.f, 0.f};
        #pragma unroll
        for (int k8 = 0; k8 < 8; ++k8) {
            float w0 = wc[k8 >> 1][2 * (k8 & 1)];
            float w1 = wc[k8 >> 1][2 * (k8 & 1) + 1];
            if (lk == 3 && k8 == 7) { w0 = 0.f; w1 = 0.f; }   // joints 62,63
            const short8v a = pack8(w0 * hx, w0 * hy, w0 * hz, w0,
                                    w1 * hx, w1 * hy, w1 * hz, w1);
            #pragma unroll
            for (int nt = 0; nt < 3; ++nt)
                acc[nt] = __builtin_amdgcn_mfma_f32_16x16x32_bf16(
                    a, breg[nt][k8], acc[nt], 0, 0, 0);
        }

        // ---- epilogue transpose (wave-private region; compiler inserts waits)
        #pragma unroll
        for (int nt = 0; nt < 3; ++nt) {
            #pragma unroll
            for (int r = 0; r < 4; ++r)
                epi[eoff[nt] + (lk * 4 + r) * 3] =
                    fmaf(acc[nt][r], sv[nt], tv[nt]);
        }

        // ---- coalesced stores: 16 regions x 24 float2
        const int m48 = mtile * 48;
        const bool edge = (m48 + 48 > OUTF);
        #pragma unroll
        for (int it = 0; it < 6; ++it) {
            const int idx = it * 64 + lane;
            const int r = idx / 24, j = idx - r * 24;
            const floatx2 val = *(const floatx2*)&epi[r * 50 + 2 * j];
            const int pp = m48 + 2 * j;
            if (!edge || pp + 1 < OUTF)
                *(floatx2*)&out[(size_t)(b0 + r) * OUTF + pp] = val;
        }
    }
}

extern "C" void kernel_launch(void* const* d_in, const int* in_sizes, int n_in,
                              void* d_out, int out_size, void* d_ws, size_t ws_size,
                              hipStream_t stream)
{
    const float* thetas  = (const float*)d_in[0];
    const float* blc     = (const float*)d_in[1];
    const float* cbl     = (const float*)d_in[2];
    const float* trans   = (const float*)d_in[3];
    const float* scale   = (const float*)d_in[4];
    const float* vtempl  = (const float*)d_in[5];
    const float* tpose   = (const float*)d_in[6];
    const float* weights = (const float*)d_in[7];
    const int*   parents = (const int*)d_in[8];
    const int*   mapper  = (const int*)d_in[9];

    float* out  = (float*)d_out;
    float* Jout = out + (size_t)256 * NV * 3;

    short* Bt = (short*)d_ws;                    // 768*KPAD bf16 = 0.39 MB

    fk_kernel<<<64, 256, 0, stream>>>(thetas, blc, cbl, trans, scale, tpose,
                                      parents, mapper, Bt, Jout);
    gemm_skin<<<768, 256, 0, stream>>>(weights, vtempl, Bt, scale, trans, out);
}

// Round 19
// 28.556 us; speedup vs baseline: 1.1286x; 1.1286x over previous
//
#include <hip/hip_runtime.h>

#define NJ     62
#define NV     14522
#define NCORE  28
#define KPAD   256    // 62*4 = 248 padded to 256 (512 B per row)
#define OUTF   (NV * 3)        // 43566
#define MT32   454             // m-tiles of 32 rows
#define EREG   100             // epi region stride (floats): 96 + 4 pad

typedef __attribute__((ext_vector_type(8))) short short8v;
typedef __attribute__((ext_vector_type(4))) short short4v;
typedef __attribute__((ext_vector_type(4))) float floatx4;
typedef __attribute__((ext_vector_type(2))) float floatx2;

#define AS1(p) ((const __attribute__((address_space(1))) void*)(p))
#define AS3(p) ((__attribute__((address_space(3))) void*)(p))

#define SCHED0() __builtin_amdgcn_sched_barrier(0)
#define WAITVM0() do { SCHED0(); asm volatile("s_waitcnt vmcnt(0)" ::: "memory"); SCHED0(); } while (0)

static __device__ inline short f2bf(float x) {
    unsigned u = __float_as_uint(x);
    unsigned r = (u + 0x7fffu + ((u >> 16) & 1u)) >> 16;
    return (short)r;
}

// pack 8 floats -> 8 bf16 (RNE) via v_cvt_pk_bf16_f32
static __device__ inline short8v pack8(float a0, float a1, float a2, float a3,
                                       float a4, float a5, float a6, float a7) {
    union { unsigned u[4]; short8v v; } p;
    asm("v_cvt_pk_bf16_f32 %0, %1, %2" : "=v"(p.u[0]) : "v"(a0), "v"(a1));
    asm("v_cvt_pk_bf16_f32 %0, %1, %2" : "=v"(p.u[1]) : "v"(a2), "v"(a3));
    asm("v_cvt_pk_bf16_f32 %0, %1, %2" : "=v"(p.u[2]) : "v"(a4), "v"(a5));
    asm("v_cvt_pk_bf16_f32 %0, %1, %2" : "=v"(p.u[3]) : "v"(a6), "v"(a7));
    return p.v;
}

// XOR swizzle over 512B rows: involution; global SOURCE at staging and LDS
// read addresses (both-sides rule). Proven in r6.
static __device__ inline unsigned swz(unsigned off) {
    return off ^ (((off >> 9) & 7u) << 4);
}

// ---------------------------------------------------------------------------
// Kernel 1: forward kinematics. 64 blocks x 256 thr; wave w = batch
// blockIdx*4+w. Writes Jout (fp32) and Bt (bf16) in the PERMUTED K layout:
//   joint j, comps m=0..3 at K-pos q = 32*((j%16)/2) + 8*(j/16) + 4*(j%2) + m
// (matches the gemm's per-lane-contiguous W mapping). Unchanged from r17.
// ---------------------------------------------------------------------------
__global__ __launch_bounds__(256) void fk_kernel(
    const float* __restrict__ thetas, const float* __restrict__ blc,
    const float* __restrict__ cbl, const float* __restrict__ trans,
    const float* __restrict__ scale, const float* __restrict__ tpose,
    const int* __restrict__ parents, const int* __restrict__ mapper,
    short* __restrict__ Bt, float* __restrict__ Jout)
{
    __shared__ float Asm[4][NJ][12];
    __shared__ float Gsm[4][NJ][12];

    const int w = threadIdx.x >> 6;
    const int b = blockIdx.x * 4 + w;
    const int k = threadIdx.x & 63;
    int p = 0;

    if (k < NJ) {
        p = parents[k];
        const float tz = thetas[(b * NJ + k) * 3 + 0];
        const float ty = thetas[(b * NJ + k) * 3 + 1];
        const float tx = thetas[(b * NJ + k) * 3 + 2];
        const float cx = cosf(tx), sx = sinf(tx);
        const float cy = cosf(ty), sy = sinf(ty);
        const float cz = cosf(tz), sz = sinf(tz);
        const float r00 = cz * cy;
        const float r01 = cz * sy * sx - sz * cx;
        const float r02 = sz * sx + cz * sy * cx;
        const float r10 = sz * cy;
        const float r11 = cz * cx + sz * sy * sx;
        const float r12 = sz * sy * cx - cz * sx;
        const float r20 = -sy;
        const float r21 = cy * sx;
        const float r22 = cy * cx;

        float f;
        const int m = mapper[k];
        if (k == 0)        f = 1.0f;
        else if (k == 1)   f = cbl[b];
        else if (m < 0)    f = 1.0f;
        else               f = 2.0f / (1.0f + expf(-blc[b * NCORE + m] * 0.2f));

        float ox, oy, oz;
        if (k == 0) {
            ox = tpose[0]; oy = tpose[1]; oz = tpose[2];
        } else {
            ox = (tpose[k * 3 + 0] - tpose[p * 3 + 0]) * f;
            oy = (tpose[k * 3 + 1] - tpose[p * 3 + 1]) * f;
            oz = (tpose[k * 3 + 2] - tpose[p * 3 + 2]) * f;
        }
        Asm[w][k][0] = r00; Asm[w][k][1] = r01; Asm[w][k][2]  = r02; Asm[w][k][3]  = ox;
        Asm[w][k][4] = r10; Asm[w][k][5] = r11; Asm[w][k][6]  = r12; Asm[w][k][7]  = oy;
        Asm[w][k][8] = r20; Asm[w][k][9] = r21; Asm[w][k][10] = r22; Asm[w][k][11] = oz;
    }
    __syncthreads();

    if (k == 0) {
        #pragma unroll
        for (int j = 0; j < 12; ++j) Gsm[w][0][j] = Asm[w][0][j];
    }
    __syncthreads();

    const int depth = (k < NJ) ? (31 - __clz((unsigned)(k + 1))) : 99;
    for (int d = 1; d <= 5; ++d) {
        if (depth == d) {
            float gp[12], a[12], g[12];
            #pragma unroll
            for (int j = 0; j < 12; ++j) { gp[j] = Gsm[w][p][j]; a[j] = Asm[w][k][j]; }
            #pragma unroll
            for (int i = 0; i < 3; ++i) {
                #pragma unroll
                for (int j = 0; j < 4; ++j) {
                    float s = (j == 3) ? gp[i * 4 + 3] : 0.0f;
                    s = fmaf(gp[i * 4 + 0], a[0 * 4 + j], s);
                    s = fmaf(gp[i * 4 + 1], a[1 * 4 + j], s);
                    s = fmaf(gp[i * 4 + 2], a[2 * 4 + j], s);
                    g[i * 4 + j] = s;
                }
            }
            #pragma unroll
            for (int j = 0; j < 12; ++j) Gsm[w][k][j] = g[j];
        }
        __syncthreads();
    }

    if (k < NJ) {
        float g[12];
        #pragma unroll
        for (int j = 0; j < 12; ++j) g[j] = Gsm[w][k][j];
        const float jx = tpose[k * 3 + 0];
        const float jy = tpose[k * 3 + 1];
        const float jz = tpose[k * 3 + 2];
        const float s  = scale[b];
        Jout[(b * NJ + k) * 3 + 0] = fmaf(g[3],  s, trans[b * 3 + 0]);
        Jout[(b * NJ + k) * 3 + 1] = fmaf(g[7],  s, trans[b * 3 + 1]);
        Jout[(b * NJ + k) * 3 + 2] = fmaf(g[11], s, trans[b * 3 + 2]);
        float np[3];
        np[0] = g[3]  - (g[0] * jx + g[1] * jy + g[2]  * jz);
        np[1] = g[7]  - (g[4] * jx + g[5] * jy + g[6]  * jz);
        np[2] = g[11] - (g[8] * jx + g[9] * jy + g[10] * jz);

        // permuted K position for this joint
        const int lkj = k >> 4;          // j / 16
        const int rr  = k & 15;
        const int qb  = 32 * (rr >> 1) + 8 * lkj + 4 * (rr & 1);
        #pragma unroll
        for (int i = 0; i < 3; ++i) {
            short4v o;
            o[0] = f2bf(g[i * 4 + 0]);
            o[1] = f2bf(g[i * 4 + 1]);
            o[2] = f2bf(g[i * 4 + 2]);
            o[3] = f2bf(np[i]);
            *(short4v*)&Bt[(size_t)(b * 3 + i) * KPAD + qb] = o;
        }
        if (k == 0) {   // zero K padding (joints 62,63 -> q 248..255)
            short4v z = {0, 0, 0, 0};
            #pragma unroll
            for (int i = 0; i < 3; ++i) {
                *(short4v*)&Bt[(size_t)(b * 3 + i) * KPAD + 248] = z;
                *(short4v*)&Bt[(size_t)(b * 3 + i) * KPAD + 252] = z;
            }
        }
    }
}

// ---------------------------------------------------------------------------
// Kernel 2: GEMM + epilogue — r17 (best: 25.1us) + m32 REGISTER-BLOCKING:
// two 16-row A-halves share each swizzled ds_read_b128 B-frag -> the
// dominant LDS-read term halves per output (288 -> 144 cy / m16-equiv).
// W gather stays coalesced (permuted K: 4 float4 per row-half) and
// prefetched one tile ahead. VGPR est ~135 <= 168 cap (256,3); the r18
// counter row gives the spill check (VGPR_Count).
// Grid 768 (3 blocks/CU), 192 stripes (70x3 + 122x2 m32-tiles) x 16 y.
// LDS: B 24KB + epi 25.6KB = 49.6KB (3 blocks/CU ok).
// ---------------------------------------------------------------------------
__global__ __launch_bounds__(256, 3) void gemm_skin(
    const float* __restrict__ W,      // (V, 62) fp32
    const float* __restrict__ vt,     // (V, 3)  fp32
    const short* __restrict__ Bt,     // (768, KPAD) bf16, permuted K
    const float* __restrict__ scale,  // (B,)
    const float* __restrict__ trans,  // (B*3,)
    float* __restrict__ out)          // (B, V, 3)
{
    __shared__ __align__(16) char ldsB[48 * 512];          // 24 KB B slab
    __shared__ __align__(16) float epi_all[4 * 16 * EREG]; // 25.6 KB epi

    const int tid  = threadIdx.x;
    const int wave = tid >> 6;
    const int lane = tid & 63;
    const int lrow = lane & 15;
    const int lk   = lane >> 4;
    const int yy    = blockIdx.x / 48;          // 0..15 (y-group)
    const int inner = blockIdx.x - yy * 48;     // 0..47
    const int s     = inner * 4 + wave;         // stripe 0..191
    const int start  = (s < 70) ? s * 3 : 210 + (s - 70) * 2;
    const int ntiles = (s < 70) ? 3 : 2;        // 70*3 + 122*2 = 454
    const int b0 = yy * 16;
    float* epi = epi_all + wave * 16 * EREG;    // 16 regions x 100 floats

    // ---- stage B slab into LDS once (global_load_lds, both-sides swizzle)
    {
        const char* Bsrc = (const char*)(Bt + (size_t)yy * 48 * KPAD);
        #pragma unroll
        for (int cc = 0; cc < 6; ++cc) {
            const unsigned Lb = (unsigned)(wave * 6144 + cc * 1024);
            __builtin_amdgcn_global_load_lds(AS1(Bsrc + swz(Lb + lane * 16)),
                                             AS3(ldsB + Lb), 16, 0, 0);
        }
    }

    // ---- per-thread invariants (while DMA in flight)
    float sv[3], tv[3]; int eoff[3];
    #pragma unroll
    for (int nt = 0; nt < 3; ++nt) {
        const int n_loc = nt * 16 + lrow;
        const int bl = n_loc / 3, ii = n_loc - bl * 3;
        eoff[nt] = bl * EREG + ii;
        sv[nt] = scale[b0 + bl];
        tv[nt] = trans[(b0 + bl) * 3 + ii];
    }
    unsigned bofs[3], bxor[3];
    #pragma unroll
    for (int nt = 0; nt < 3; ++nt) {
        const unsigned brow = nt * 16 + lrow;
        bofs[nt] = brow * 512;
        bxor[nt] = (brow & 7u) << 4;
    }

    // ---- prefetch tile 0's W (both halves) + vt rows
    floatx4 wc0[4], wc1[4]; float h0x, h0y, h0z, h1x, h1y, h1z;
    {
        int vr0 = start * 32 + lrow;      if (vr0 > NV - 1) vr0 = NV - 1;
        int vr1 = start * 32 + 16 + lrow; if (vr1 > NV - 1) vr1 = NV - 1;
        const float* Wb0 = W + (size_t)vr0 * NJ + lk * 16;
        const float* Wb1 = W + (size_t)vr1 * NJ + lk * 16;
        #pragma unroll
        for (int c = 0; c < 4; ++c) {
            wc0[c] = *(const floatx4*)(Wb0 + 4 * c);
            wc1[c] = *(const floatx4*)(Wb1 + 4 * c);
        }
        h0x = vt[vr0 * 3 + 0]; h0y = vt[vr0 * 3 + 1]; h0z = vt[vr0 * 3 + 2];
        h1x = vt[vr1 * 3 + 0]; h1y = vt[vr1 * 3 + 1]; h1z = vt[vr1 * 3 + 2];
    }

    WAITVM0();
    __syncthreads();    // B slab resident; read-only hereafter

    for (int t = 0; t < ntiles; ++t) {
        // ---- issue prefetch for tile t+1 (hidden under MFMA/epi/store)
        floatx4 wn0[4], wn1[4];
        float g0x = 0.f, g0y = 0.f, g0z = 0.f, g1x = 0.f, g1y = 0.f, g1z = 0.f;
        if (t + 1 < ntiles) {
            int vr0 = (start + t + 1) * 32 + lrow;      if (vr0 > NV - 1) vr0 = NV - 1;
            int vr1 = (start + t + 1) * 32 + 16 + lrow; if (vr1 > NV - 1) vr1 = NV - 1;
            const float* Wb0 = W + (size_t)vr0 * NJ + lk * 16;
            const float* Wb1 = W + (size_t)vr1 * NJ + lk * 16;
            #pragma unroll
            for (int c = 0; c < 4; ++c) {
                wn0[c] = *(const floatx4*)(Wb0 + 4 * c);
                wn1[c] = *(const floatx4*)(Wb1 + 4 * c);
            }
            g0x = vt[vr0 * 3 + 0]; g0y = vt[vr0 * 3 + 1]; g0z = vt[vr0 * 3 + 2];
            g1x = vt[vr1 * 3 + 0]; g1y = vt[vr1 * 3 + 1]; g1z = vt[vr1 * 3 + 2];
        } else {
            #pragma unroll
            for (int c = 0; c < 4; ++c) {
                wn0[c] = (floatx4){0.f, 0.f, 0.f, 0.f};
                wn1[c] = (floatx4){0.f, 0.f, 0.f, 0.f};
            }
        }

        // ---- MFMA: each B frag read ONCE, feeds both m-halves
        floatx4 acc0[3], acc1[3];
        #pragma unroll
        for (int nt = 0; nt < 3; ++nt) {
            acc0[nt] = (floatx4){0.f, 0.f, 0.f, 0.f};
            acc1[nt] = (floatx4){0.f, 0.f, 0.f, 0.f};
        }
        #pragma unroll
        for (int k8 = 0; k8 < 8; ++k8) {
            float w00 = wc0[k8 >> 1][2 * (k8 & 1)];
            float w01 = wc0[k8 >> 1][2 * (k8 & 1) + 1];
            float w10 = wc1[k8 >> 1][2 * (k8 & 1)];
            float w11 = wc1[k8 >> 1][2 * (k8 & 1) + 1];
            if (lk == 3 && k8 == 7) { w00 = w01 = w10 = w11 = 0.f; }  // joints 62,63
            const short8v a0 = pack8(w00 * h0x, w00 * h0y, w00 * h0z, w00,
                                     w01 * h0x, w01 * h0y, w01 * h0z, w01);
            const short8v a1 = pack8(w10 * h1x, w10 * h1y, w10 * h1z, w10,
                                     w11 * h1x, w11 * h1y, w11 * h1z, w11);
            const unsigned cb = (unsigned)(k8 * 4 + lk) * 16;
            #pragma unroll
            for (int nt = 0; nt < 3; ++nt) {
                const short8v bf = *(const short8v*)(ldsB + bofs[nt] + (cb ^ bxor[nt]));
                acc0[nt] = __builtin_amdgcn_mfma_f32_16x16x32_bf16(a0, bf, acc0[nt], 0, 0, 0);
                acc1[nt] = __builtin_amdgcn_mfma_f32_16x16x32_bf16(a1, bf, acc1[nt], 0, 0, 0);
            }
        }

        // ---- epilogue transpose (wave-private region), both halves
        #pragma unroll
        for (int nt = 0; nt < 3; ++nt) {
            #pragma unroll
            for (int r = 0; r < 4; ++r) {
                const int m0 = (lk * 4 + r) * 3;
                epi[eoff[nt] + m0]      = fmaf(acc0[nt][r], sv[nt], tv[nt]);
                epi[eoff[nt] + 48 + m0] = fmaf(acc1[nt][r], sv[nt], tv[nt]);
            }
        }

        // ---- coalesced stores: 16 regions x 48 float2 (12 per lane)
        const int m96 = (start + t) * 96;
        const bool edge = (m96 + 96 > OUTF);    // only tile 453
        #pragma unroll
        for (int it = 0; it < 12; ++it) {
            const int idx = it * 64 + lane;
            const int r = idx / 48, j = idx - r * 48;
            const floatx2 val = *(const floatx2*)&epi[r * EREG + 2 * j];
            const int pp = m96 + 2 * j;
            if (!edge || pp + 1 < OUTF)
                *(floatx2*)&out[(size_t)(b0 + r) * OUTF + pp] = val;
        }

        // ---- rotate prefetch
        #pragma unroll
        for (int c = 0; c < 4; ++c) { wc0[c] = wn0[c]; wc1[c] = wn1[c]; }
        h0x = g0x; h0y = g0y; h0z = g0z;
        h1x = g1x; h1y = g1y; h1z = g1z;
    }
}

extern "C" void kernel_launch(void* const* d_in, const int* in_sizes, int n_in,
                              void* d_out, int out_size, void* d_ws, size_t ws_size,
                              hipStream_t stream)
{
    const float* thetas  = (const float*)d_in[0];
    const float* blc     = (const float*)d_in[1];
    const float* cbl     = (const float*)d_in[2];
    const float* trans   = (const float*)d_in[3];
    const float* scale   = (const float*)d_in[4];
    const float* vtempl  = (const float*)d_in[5];
    const float* tpose   = (const float*)d_in[6];
    const float* weights = (const float*)d_in[7];
    const int*   parents = (const int*)d_in[8];
    const int*   mapper  = (const int*)d_in[9];

    float* out  = (float*)d_out;
    float* Jout = out + (size_t)256 * NV * 3;

    short* Bt = (short*)d_ws;                    // 768*KPAD bf16 = 0.39 MB

    fk_kernel<<<64, 256, 0, stream>>>(thetas, blc, cbl, trans, scale, tpose,
                                      parents, mapper, Bt, Jout);
    gemm_skin<<<768, 256, 0, stream>>>(weights, vtempl, Bt, scale, trans, out);
}

// Round 20
// 25.127 us; speedup vs baseline: 1.2826x; 1.1365x over previous
//
#include <hip/hip_runtime.h>

#define NJ     62
#define NV     14522
#define NCORE  28
#define KPAD   256    // 62*4 = 248 padded to 256 (512 B per row)
#define OUTF   (NV * 3)        // 43566
#define MT     908             // m-tiles of 16 rows
#define NSTR   192             // stripes: 140 of 5 tiles, 52 of 4

typedef __attribute__((ext_vector_type(8))) short short8v;
typedef __attribute__((ext_vector_type(4))) short short4v;
typedef __attribute__((ext_vector_type(4))) float floatx4;
typedef __attribute__((ext_vector_type(2))) float floatx2;

#define AS1(p) ((const __attribute__((address_space(1))) void*)(p))
#define AS3(p) ((__attribute__((address_space(3))) void*)(p))

#define SCHED0() __builtin_amdgcn_sched_barrier(0)
#define WAITVM0() do { SCHED0(); asm volatile("s_waitcnt vmcnt(0)" ::: "memory"); SCHED0(); } while (0)

static __device__ inline short f2bf(float x) {
    unsigned u = __float_as_uint(x);
    unsigned r = (u + 0x7fffu + ((u >> 16) & 1u)) >> 16;
    return (short)r;
}

// pack 8 floats -> 8 bf16 (RNE) via v_cvt_pk_bf16_f32
static __device__ inline short8v pack8(float a0, float a1, float a2, float a3,
                                       float a4, float a5, float a6, float a7) {
    union { unsigned u[4]; short8v v; } p;
    asm("v_cvt_pk_bf16_f32 %0, %1, %2" : "=v"(p.u[0]) : "v"(a0), "v"(a1));
    asm("v_cvt_pk_bf16_f32 %0, %1, %2" : "=v"(p.u[1]) : "v"(a2), "v"(a3));
    asm("v_cvt_pk_bf16_f32 %0, %1, %2" : "=v"(p.u[2]) : "v"(a4), "v"(a5));
    asm("v_cvt_pk_bf16_f32 %0, %1, %2" : "=v"(p.u[3]) : "v"(a6), "v"(a7));
    return p.v;
}

// XOR swizzle over 512B rows: involution; global SOURCE at staging and LDS
// read addresses (both-sides rule). Proven in r6.
static __device__ inline unsigned swz(unsigned off) {
    return off ^ (((off >> 9) & 7u) << 4);
}

// ---------------------------------------------------------------------------
// Kernel 1: forward kinematics. 64 blocks x 256 thr; wave w = batch
// blockIdx*4+w. Writes Jout (fp32) and Bt (bf16) in the PERMUTED K layout:
//   joint j, comps m=0..3 at K-pos q = 32*((j%16)/2) + 8*(j/16) + 4*(j%2) + m
// (matches the gemm's per-lane-contiguous W mapping). Unchanged from r17.
// ---------------------------------------------------------------------------
__global__ __launch_bounds__(256) void fk_kernel(
    const float* __restrict__ thetas, const float* __restrict__ blc,
    const float* __restrict__ cbl, const float* __restrict__ trans,
    const float* __restrict__ scale, const float* __restrict__ tpose,
    const int* __restrict__ parents, const int* __restrict__ mapper,
    short* __restrict__ Bt, float* __restrict__ Jout)
{
    __shared__ float Asm[4][NJ][12];
    __shared__ float Gsm[4][NJ][12];

    const int w = threadIdx.x >> 6;
    const int b = blockIdx.x * 4 + w;
    const int k = threadIdx.x & 63;
    int p = 0;

    if (k < NJ) {
        p = parents[k];
        const float tz = thetas[(b * NJ + k) * 3 + 0];
        const float ty = thetas[(b * NJ + k) * 3 + 1];
        const float tx = thetas[(b * NJ + k) * 3 + 2];
        const float cx = cosf(tx), sx = sinf(tx);
        const float cy = cosf(ty), sy = sinf(ty);
        const float cz = cosf(tz), sz = sinf(tz);
        const float r00 = cz * cy;
        const float r01 = cz * sy * sx - sz * cx;
        const float r02 = sz * sx + cz * sy * cx;
        const float r10 = sz * cy;
        const float r11 = cz * cx + sz * sy * sx;
        const float r12 = sz * sy * cx - cz * sx;
        const float r20 = -sy;
        const float r21 = cy * sx;
        const float r22 = cy * cx;

        float f;
        const int m = mapper[k];
        if (k == 0)        f = 1.0f;
        else if (k == 1)   f = cbl[b];
        else if (m < 0)    f = 1.0f;
        else               f = 2.0f / (1.0f + expf(-blc[b * NCORE + m] * 0.2f));

        float ox, oy, oz;
        if (k == 0) {
            ox = tpose[0]; oy = tpose[1]; oz = tpose[2];
        } else {
            ox = (tpose[k * 3 + 0] - tpose[p * 3 + 0]) * f;
            oy = (tpose[k * 3 + 1] - tpose[p * 3 + 1]) * f;
            oz = (tpose[k * 3 + 2] - tpose[p * 3 + 2]) * f;
        }
        Asm[w][k][0] = r00; Asm[w][k][1] = r01; Asm[w][k][2]  = r02; Asm[w][k][3]  = ox;
        Asm[w][k][4] = r10; Asm[w][k][5] = r11; Asm[w][k][6]  = r12; Asm[w][k][7]  = oy;
        Asm[w][k][8] = r20; Asm[w][k][9] = r21; Asm[w][k][10] = r22; Asm[w][k][11] = oz;
    }
    __syncthreads();

    if (k == 0) {
        #pragma unroll
        for (int j = 0; j < 12; ++j) Gsm[w][0][j] = Asm[w][0][j];
    }
    __syncthreads();

    const int depth = (k < NJ) ? (31 - __clz((unsigned)(k + 1))) : 99;
    for (int d = 1; d <= 5; ++d) {
        if (depth == d) {
            float gp[12], a[12], g[12];
            #pragma unroll
            for (int j = 0; j < 12; ++j) { gp[j] = Gsm[w][p][j]; a[j] = Asm[w][k][j]; }
            #pragma unroll
            for (int i = 0; i < 3; ++i) {
                #pragma unroll
                for (int j = 0; j < 4; ++j) {
                    float s = (j == 3) ? gp[i * 4 + 3] : 0.0f;
                    s = fmaf(gp[i * 4 + 0], a[0 * 4 + j], s);
                    s = fmaf(gp[i * 4 + 1], a[1 * 4 + j], s);
                    s = fmaf(gp[i * 4 + 2], a[2 * 4 + j], s);
                    g[i * 4 + j] = s;
                }
            }
            #pragma unroll
            for (int j = 0; j < 12; ++j) Gsm[w][k][j] = g[j];
        }
        __syncthreads();
    }

    if (k < NJ) {
        float g[12];
        #pragma unroll
        for (int j = 0; j < 12; ++j) g[j] = Gsm[w][k][j];
        const float jx = tpose[k * 3 + 0];
        const float jy = tpose[k * 3 + 1];
        const float jz = tpose[k * 3 + 2];
        const float s  = scale[b];
        Jout[(b * NJ + k) * 3 + 0] = fmaf(g[3],  s, trans[b * 3 + 0]);
        Jout[(b * NJ + k) * 3 + 1] = fmaf(g[7],  s, trans[b * 3 + 1]);
        Jout[(b * NJ + k) * 3 + 2] = fmaf(g[11], s, trans[b * 3 + 2]);
        float np[3];
        np[0] = g[3]  - (g[0] * jx + g[1] * jy + g[2]  * jz);
        np[1] = g[7]  - (g[4] * jx + g[5] * jy + g[6]  * jz);
        np[2] = g[11] - (g[8] * jx + g[9] * jy + g[10] * jz);

        // permuted K position for this joint
        const int lkj = k >> 4;          // j / 16
        const int rr  = k & 15;
        const int qb  = 32 * (rr >> 1) + 8 * lkj + 4 * (rr & 1);
        #pragma unroll
        for (int i = 0; i < 3; ++i) {
            short4v o;
            o[0] = f2bf(g[i * 4 + 0]);
            o[1] = f2bf(g[i * 4 + 1]);
            o[2] = f2bf(g[i * 4 + 2]);
            o[3] = f2bf(np[i]);
            *(short4v*)&Bt[(size_t)(b * 3 + i) * KPAD + qb] = o;
        }
        if (k == 0) {   // zero K padding (joints 62,63 -> q 248..255)
            short4v z = {0, 0, 0, 0};
            #pragma unroll
            for (int i = 0; i < 3; ++i) {
                *(short4v*)&Bt[(size_t)(b * 3 + i) * KPAD + 248] = z;
                *(short4v*)&Bt[(size_t)(b * 3 + i) * KPAD + 252] = z;
            }
        }
    }
}

// ---------------------------------------------------------------------------
// Kernel 2: GEMM + epilogue — r17's best kernel (25.1us), verbatim, plus
// s_setprio(1) around the MFMA cluster (T5): barrier-free waves sit at
// different phases per SIMD, so priority lets MFMA-phase waves win issue
// arbitration over gather/store-phase waves. Zero structural change.
//  - permuted K layout: each lane's 16 W weights contiguous (4 float4).
//  - W/vt prefetch for tile t+1 before tile t's MFMA phase.
//  - B slab in LDS (24 KB, staged once, swizzled); A frags inline.
// Grid 768 (3 blocks/CU, 3 waves/SIMD), 192 stripes x 16 y-groups.
// ---------------------------------------------------------------------------
__global__ __launch_bounds__(256, 3) void gemm_skin(
    const float* __restrict__ W,      // (V, 62) fp32
    const float* __restrict__ vt,     // (V, 3)  fp32
    const short* __restrict__ Bt,     // (768, KPAD) bf16, permuted K
    const float* __restrict__ scale,  // (B,)
    const float* __restrict__ trans,  // (B*3,)
    float* __restrict__ out)          // (B, V, 3)
{
    __shared__ __align__(16) char ldsB[48 * 512];       // 24 KB B slab
    __shared__ __align__(16) float epi_all[4 * 800];    // 12.8 KB epi

    const int tid  = threadIdx.x;
    const int wave = tid >> 6;
    const int lane = tid & 63;
    const int lrow = lane & 15;
    const int lk   = lane >> 4;
    const int yy    = blockIdx.x / 48;          // 0..15 (y-group)
    const int inner = blockIdx.x - yy * 48;     // 0..47
    const int s     = inner * 4 + wave;         // stripe 0..191
    const int start  = s * 4 + (s < 140 ? s : 140);
    const int ntiles = 4 + (s < 140 ? 1 : 0);   // 140*5 + 52*4 = 908
    const int b0 = yy * 16;
    float* epi = epi_all + wave * 800;          // 16 regions x 50 floats

    // ---- stage B slab into LDS once (global_load_lds, both-sides swizzle)
    {
        const char* Bsrc = (const char*)(Bt + (size_t)yy * 48 * KPAD);
        #pragma unroll
        for (int cc = 0; cc < 6; ++cc) {
            const unsigned Lb = (unsigned)(wave * 6144 + cc * 1024);
            __builtin_amdgcn_global_load_lds(AS1(Bsrc + swz(Lb + lane * 16)),
                                             AS3(ldsB + Lb), 16, 0, 0);
        }
    }

    // ---- per-thread invariants (while DMA in flight)
    float sv[3], tv[3]; int eoff[3];
    #pragma unroll
    for (int nt = 0; nt < 3; ++nt) {
        const int n_loc = nt * 16 + lrow;
        const int bl = n_loc / 3, ii = n_loc - bl * 3;
        eoff[nt] = bl * 50 + ii;
        sv[nt] = scale[b0 + bl];
        tv[nt] = trans[(b0 + bl) * 3 + ii];
    }
    unsigned bofs[3], bxor[3];
    #pragma unroll
    for (int nt = 0; nt < 3; ++nt) {
        const unsigned brow = nt * 16 + lrow;
        bofs[nt] = brow * 512;
        bxor[nt] = (brow & 7u) << 4;
    }

    // ---- prefetch tile 0's W (4 coalesced float4: 16 contiguous weights
    //      at W[row] + 16*lk) and vt row
    floatx4 wc[4]; float hcx, hcy, hcz;
    {
        int vrow = start * 16 + lrow;
        if (vrow > NV - 1) vrow = NV - 1;
        const float* Wb = W + (size_t)vrow * NJ + lk * 16;
        wc[0] = *(const floatx4*)(Wb + 0);
        wc[1] = *(const floatx4*)(Wb + 4);
        wc[2] = *(const floatx4*)(Wb + 8);
        wc[3] = *(const floatx4*)(Wb + 12);
        hcx = vt[vrow * 3 + 0]; hcy = vt[vrow * 3 + 1]; hcz = vt[vrow * 3 + 2];
    }

    WAITVM0();
    __syncthreads();    // B slab resident; read-only hereafter

    for (int t = 0; t < ntiles; ++t) {
        // ---- issue prefetch for tile t+1 (latency hidden under MFMA/epi/store)
        floatx4 wn[4]; float hnx = 0.f, hny = 0.f, hnz = 0.f;
        if (t + 1 < ntiles) {
            int vr = (start + t + 1) * 16 + lrow;
            if (vr > NV - 1) vr = NV - 1;
            const float* Wb = W + (size_t)vr * NJ + lk * 16;
            wn[0] = *(const floatx4*)(Wb + 0);
            wn[1] = *(const floatx4*)(Wb + 4);
            wn[2] = *(const floatx4*)(Wb + 8);
            wn[3] = *(const floatx4*)(Wb + 12);
            hnx = vt[vr * 3 + 0]; hny = vt[vr * 3 + 1]; hnz = vt[vr * 3 + 2];
        } else {
            wn[0] = wn[1] = wn[2] = wn[3] = (floatx4){0.f, 0.f, 0.f, 0.f};
        }

        // ---- MFMA: A frag built inline per k8 from contiguous weights;
        //      B frags from LDS (swizzled ds_read_b128). T5: boost priority
        //      through the matrix-pipe cluster.
        floatx4 acc[3];
        #pragma unroll
        for (int nt = 0; nt < 3; ++nt) acc[nt] = (floatx4){0.f, 0.f, 0.f, 0.f};
        __builtin_amdgcn_s_setprio(1);
        #pragma unroll
        for (int k8 = 0; k8 < 8; ++k8) {
            // joints 16*lk + 2*k8, +1  ->  wc[k8/2][2*(k8%2)], [..+1]
            float w0 = wc[k8 >> 1][2 * (k8 & 1)];
            float w1 = wc[k8 >> 1][2 * (k8 & 1) + 1];
            if (lk == 3 && k8 == 7) { w0 = 0.f; w1 = 0.f; }   // joints 62,63
            const short8v a = pack8(w0 * hcx, w0 * hcy, w0 * hcz, w0,
                                    w1 * hcx, w1 * hcy, w1 * hcz, w1);
            const unsigned cb = (unsigned)(k8 * 4 + lk) * 16;
            #pragma unroll
            for (int nt = 0; nt < 3; ++nt) {
                const short8v bf = *(const short8v*)(ldsB + bofs[nt] + (cb ^ bxor[nt]));
                acc[nt] = __builtin_amdgcn_mfma_f32_16x16x32_bf16(
                    a, bf, acc[nt], 0, 0, 0);
            }
        }
        __builtin_amdgcn_s_setprio(0);

        // ---- epilogue transpose (wave-private region)
        #pragma unroll
        for (int nt = 0; nt < 3; ++nt) {
            #pragma unroll
            for (int r = 0; r < 4; ++r)
                epi[eoff[nt] + (lk * 4 + r) * 3] =
                    fmaf(acc[nt][r], sv[nt], tv[nt]);
        }

        // ---- coalesced stores: 16 regions x 24 float2
        const int m48 = (start + t) * 48;
        const bool edge = (m48 + 48 > OUTF);
        #pragma unroll
        for (int it = 0; it < 6; ++it) {
            const int idx = it * 64 + lane;
            const int r = idx / 24, j = idx - r * 24;
            const floatx2 val = *(const floatx2*)&epi[r * 50 + 2 * j];
            const int pp = m48 + 2 * j;
            if (!edge || pp + 1 < OUTF)
                *(floatx2*)&out[(size_t)(b0 + r) * OUTF + pp] = val;
        }

        // ---- rotate prefetch
        wc[0] = wn[0]; wc[1] = wn[1]; wc[2] = wn[2]; wc[3] = wn[3];
        hcx = hnx; hcy = hny; hcz = hnz;
    }
}

extern "C" void kernel_launch(void* const* d_in, const int* in_sizes, int n_in,
                              void* d_out, int out_size, void* d_ws, size_t ws_size,
                              hipStream_t stream)
{
    const float* thetas  = (const float*)d_in[0];
    const float* blc     = (const float*)d_in[1];
    const float* cbl     = (const float*)d_in[2];
    const float* trans   = (const float*)d_in[3];
    const float* scale   = (const float*)d_in[4];
    const float* vtempl  = (const float*)d_in[5];
    const float* tpose   = (const float*)d_in[6];
    const float* weights = (const float*)d_in[7];
    const int*   parents = (const int*)d_in[8];
    const int*   mapper  = (const int*)d_in[9];

    float* out  = (float*)d_out;
    float* Jout = out + (size_t)256 * NV * 3;

    short* Bt = (short*)d_ws;                    // 768*KPAD bf16 = 0.39 MB

    fk_kernel<<<64, 256, 0, stream>>>(thetas, blc, cbl, trans, scale, tpose,
                                      parents, mapper, Bt, Jout);
    gemm_skin<<<768, 256, 0, stream>>>(weights, vtempl, Bt, scale, trans, out);
}

// Round 21
// 24.950 us; speedup vs baseline: 1.2918x; 1.0071x over previous
//
#include <hip/hip_runtime.h>

#define NJ     62
#define NV     14522
#define NCORE  28
#define KPAD   256    // 62*4 = 248 padded to 256 (512 B per row)
#define OUTF   (NV * 3)        // 43566
#define MT     908             // m-tiles of 16 rows
#define NSTR   192             // stripes: 140 of 5 tiles, 52 of 4

typedef __attribute__((ext_vector_type(8))) short short8v;
typedef __attribute__((ext_vector_type(4))) short short4v;
typedef __attribute__((ext_vector_type(4))) float floatx4;
typedef __attribute__((ext_vector_type(2))) float floatx2;

#define AS1(p) ((const __attribute__((address_space(1))) void*)(p))
#define AS3(p) ((__attribute__((address_space(3))) void*)(p))

#define SCHED0() __builtin_amdgcn_sched_barrier(0)
#define WAITVM0() do { SCHED0(); asm volatile("s_waitcnt vmcnt(0)" ::: "memory"); SCHED0(); } while (0)

static __device__ inline short f2bf(float x) {
    unsigned u = __float_as_uint(x);
    unsigned r = (u + 0x7fffu + ((u >> 16) & 1u)) >> 16;
    return (short)r;
}

// pack 8 floats -> 8 bf16 (RNE) via v_cvt_pk_bf16_f32
static __device__ inline short8v pack8(float a0, float a1, float a2, float a3,
                                       float a4, float a5, float a6, float a7) {
    union { unsigned u[4]; short8v v; } p;
    asm("v_cvt_pk_bf16_f32 %0, %1, %2" : "=v"(p.u[0]) : "v"(a0), "v"(a1));
    asm("v_cvt_pk_bf16_f32 %0, %1, %2" : "=v"(p.u[1]) : "v"(a2), "v"(a3));
    asm("v_cvt_pk_bf16_f32 %0, %1, %2" : "=v"(p.u[2]) : "v"(a4), "v"(a5));
    asm("v_cvt_pk_bf16_f32 %0, %1, %2" : "=v"(p.u[3]) : "v"(a6), "v"(a7));
    return p.v;
}

// XOR swizzle over 512B rows: involution; global SOURCE at staging and LDS
// read addresses (both-sides rule). Proven in r6.
static __device__ inline unsigned swz(unsigned off) {
    return off ^ (((off >> 9) & 7u) << 4);
}

// ---------------------------------------------------------------------------
// Kernel 1: forward kinematics. 64 blocks x 256 thr; wave w = batch
// blockIdx*4+w. Writes Jout (fp32) and Bt (bf16) in the PERMUTED K layout:
//   joint j, comps m=0..3 at K-pos q = 32*((j%16)/2) + 8*(j/16) + 4*(j%2) + m
// (matches the gemm's per-lane-contiguous W mapping). Unchanged from r17.
// ---------------------------------------------------------------------------
__global__ __launch_bounds__(256) void fk_kernel(
    const float* __restrict__ thetas, const float* __restrict__ blc,
    const float* __restrict__ cbl, const float* __restrict__ trans,
    const float* __restrict__ scale, const float* __restrict__ tpose,
    const int* __restrict__ parents, const int* __restrict__ mapper,
    short* __restrict__ Bt, float* __restrict__ Jout)
{
    __shared__ float Asm[4][NJ][12];
    __shared__ float Gsm[4][NJ][12];

    const int w = threadIdx.x >> 6;
    const int b = blockIdx.x * 4 + w;
    const int k = threadIdx.x & 63;
    int p = 0;

    if (k < NJ) {
        p = parents[k];
        const float tz = thetas[(b * NJ + k) * 3 + 0];
        const float ty = thetas[(b * NJ + k) * 3 + 1];
        const float tx = thetas[(b * NJ + k) * 3 + 2];
        const float cx = cosf(tx), sx = sinf(tx);
        const float cy = cosf(ty), sy = sinf(ty);
        const float cz = cosf(tz), sz = sinf(tz);
        const float r00 = cz * cy;
        const float r01 = cz * sy * sx - sz * cx;
        const float r02 = sz * sx + cz * sy * cx;
        const float r10 = sz * cy;
        const float r11 = cz * cx + sz * sy * sx;
        const float r12 = sz * sy * cx - cz * sx;
        const float r20 = -sy;
        const float r21 = cy * sx;
        const float r22 = cy * cx;

        float f;
        const int m = mapper[k];
        if (k == 0)        f = 1.0f;
        else if (k == 1)   f = cbl[b];
        else if (m < 0)    f = 1.0f;
        else               f = 2.0f / (1.0f + expf(-blc[b * NCORE + m] * 0.2f));

        float ox, oy, oz;
        if (k == 0) {
            ox = tpose[0]; oy = tpose[1]; oz = tpose[2];
        } else {
            ox = (tpose[k * 3 + 0] - tpose[p * 3 + 0]) * f;
            oy = (tpose[k * 3 + 1] - tpose[p * 3 + 1]) * f;
            oz = (tpose[k * 3 + 2] - tpose[p * 3 + 2]) * f;
        }
        Asm[w][k][0] = r00; Asm[w][k][1] = r01; Asm[w][k][2]  = r02; Asm[w][k][3]  = ox;
        Asm[w][k][4] = r10; Asm[w][k][5] = r11; Asm[w][k][6]  = r12; Asm[w][k][7]  = oy;
        Asm[w][k][8] = r20; Asm[w][k][9] = r21; Asm[w][k][10] = r22; Asm[w][k][11] = oz;
    }
    __syncthreads();

    if (k == 0) {
        #pragma unroll
        for (int j = 0; j < 12; ++j) Gsm[w][0][j] = Asm[w][0][j];
    }
    __syncthreads();

    const int depth = (k < NJ) ? (31 - __clz((unsigned)(k + 1))) : 99;
    for (int d = 1; d <= 5; ++d) {
        if (depth == d) {
            float gp[12], a[12], g[12];
            #pragma unroll
            for (int j = 0; j < 12; ++j) { gp[j] = Gsm[w][p][j]; a[j] = Asm[w][k][j]; }
            #pragma unroll
            for (int i = 0; i < 3; ++i) {
                #pragma unroll
                for (int j = 0; j < 4; ++j) {
                    float s = (j == 3) ? gp[i * 4 + 3] : 0.0f;
                    s = fmaf(gp[i * 4 + 0], a[0 * 4 + j], s);
                    s = fmaf(gp[i * 4 + 1], a[1 * 4 + j], s);
                    s = fmaf(gp[i * 4 + 2], a[2 * 4 + j], s);
                    g[i * 4 + j] = s;
                }
            }
            #pragma unroll
            for (int j = 0; j < 12; ++j) Gsm[w][k][j] = g[j];
        }
        __syncthreads();
    }

    if (k < NJ) {
        float g[12];
        #pragma unroll
        for (int j = 0; j < 12; ++j) g[j] = Gsm[w][k][j];
        const float jx = tpose[k * 3 + 0];
        const float jy = tpose[k * 3 + 1];
        const float jz = tpose[k * 3 + 2];
        const float s  = scale[b];
        Jout[(b * NJ + k) * 3 + 0] = fmaf(g[3],  s, trans[b * 3 + 0]);
        Jout[(b * NJ + k) * 3 + 1] = fmaf(g[7],  s, trans[b * 3 + 1]);
        Jout[(b * NJ + k) * 3 + 2] = fmaf(g[11], s, trans[b * 3 + 2]);
        float np[3];
        np[0] = g[3]  - (g[0] * jx + g[1] * jy + g[2]  * jz);
        np[1] = g[7]  - (g[4] * jx + g[5] * jy + g[6]  * jz);
        np[2] = g[11] - (g[8] * jx + g[9] * jy + g[10] * jz);

        // permuted K position for this joint
        const int lkj = k >> 4;          // j / 16
        const int rr  = k & 15;
        const int qb  = 32 * (rr >> 1) + 8 * lkj + 4 * (rr & 1);
        #pragma unroll
        for (int i = 0; i < 3; ++i) {
            short4v o;
            o[0] = f2bf(g[i * 4 + 0]);
            o[1] = f2bf(g[i * 4 + 1]);
            o[2] = f2bf(g[i * 4 + 2]);
            o[3] = f2bf(np[i]);
            *(short4v*)&Bt[(size_t)(b * 3 + i) * KPAD + qb] = o;
        }
        if (k == 0) {   // zero K padding (joints 62,63 -> q 248..255)
            short4v z = {0, 0, 0, 0};
            #pragma unroll
            for (int i = 0; i < 3; ++i) {
                *(short4v*)&Bt[(size_t)(b * 3 + i) * KPAD + 248] = z;
                *(short4v*)&Bt[(size_t)(b * 3 + i) * KPAD + 252] = z;
            }
        }
    }
}

// ---------------------------------------------------------------------------
// Kernel 2: GEMM + epilogue — r17/r20 best (25.1us) + DEFERRED STORES:
// wave-private epi region ping-pongs (2x800 floats); tile t's stores are
// issued at the top of iteration t+1 from the other buffer, so the serial
// {ds_write -> lgkm drain -> ds_read -> global store} tail overlaps the
// next tile's pack/MFMA instead of blocking it. No barriers, no extra
// VGPR (values flow LDS -> store). Everything else r20-identical.
// Grid 768 (3 blocks/CU, 3 waves/SIMD); LDS = 24KB B + 25.6KB epi = 49.7KB.
// ---------------------------------------------------------------------------
__global__ __launch_bounds__(256, 3) void gemm_skin(
    const float* __restrict__ W,      // (V, 62) fp32
    const float* __restrict__ vt,     // (V, 3)  fp32
    const short* __restrict__ Bt,     // (768, KPAD) bf16, permuted K
    const float* __restrict__ scale,  // (B,)
    const float* __restrict__ trans,  // (B*3,)
    float* __restrict__ out)          // (B, V, 3)
{
    __shared__ __align__(16) char ldsB[48 * 512];       // 24 KB B slab
    __shared__ __align__(16) float epi_all[4 * 1600];   // 25.6 KB epi (2 bufs/wave)

    const int tid  = threadIdx.x;
    const int wave = tid >> 6;
    const int lane = tid & 63;
    const int lrow = lane & 15;
    const int lk   = lane >> 4;
    const int yy    = blockIdx.x / 48;          // 0..15 (y-group)
    const int inner = blockIdx.x - yy * 48;     // 0..47
    const int s     = inner * 4 + wave;         // stripe 0..191
    const int start  = s * 4 + (s < 140 ? s : 140);
    const int ntiles = 4 + (s < 140 ? 1 : 0);   // 140*5 + 52*4 = 908
    const int b0 = yy * 16;
    float* epi0 = epi_all + wave * 1600;        // buf A: 16 regions x 50 f
    float* epi1 = epi0 + 800;                   // buf B

    // ---- stage B slab into LDS once (global_load_lds, both-sides swizzle)
    {
        const char* Bsrc = (const char*)(Bt + (size_t)yy * 48 * KPAD);
        #pragma unroll
        for (int cc = 0; cc < 6; ++cc) {
            const unsigned Lb = (unsigned)(wave * 6144 + cc * 1024);
            __builtin_amdgcn_global_load_lds(AS1(Bsrc + swz(Lb + lane * 16)),
                                             AS3(ldsB + Lb), 16, 0, 0);
        }
    }

    // ---- per-thread invariants (while DMA in flight)
    float sv[3], tv[3]; int eoff[3];
    #pragma unroll
    for (int nt = 0; nt < 3; ++nt) {
        const int n_loc = nt * 16 + lrow;
        const int bl = n_loc / 3, ii = n_loc - bl * 3;
        eoff[nt] = bl * 50 + ii;
        sv[nt] = scale[b0 + bl];
        tv[nt] = trans[(b0 + bl) * 3 + ii];
    }
    unsigned bofs[3], bxor[3];
    #pragma unroll
    for (int nt = 0; nt < 3; ++nt) {
        const unsigned brow = nt * 16 + lrow;
        bofs[nt] = brow * 512;
        bxor[nt] = (brow & 7u) << 4;
    }

    // deferred-store helper: flush tile tt from buffer ebuf
    auto do_store = [&](int tt, const float* ebuf) {
        const int m48 = (start + tt) * 48;
        const bool edge = (m48 + 48 > OUTF);
        #pragma unroll
        for (int it = 0; it < 6; ++it) {
            const int idx = it * 64 + lane;
            const int r = idx / 24, j = idx - r * 24;
            const floatx2 val = *(const floatx2*)&ebuf[r * 50 + 2 * j];
            const int pp = m48 + 2 * j;
            if (!edge || pp + 1 < OUTF)
                *(floatx2*)&out[(size_t)(b0 + r) * OUTF + pp] = val;
        }
    };

    // ---- prefetch tile 0's W (4 coalesced float4: 16 contiguous weights
    //      at W[row] + 16*lk) and vt row
    floatx4 wc[4]; float hcx, hcy, hcz;
    {
        int vrow = start * 16 + lrow;
        if (vrow > NV - 1) vrow = NV - 1;
        const float* Wb = W + (size_t)vrow * NJ + lk * 16;
        wc[0] = *(const floatx4*)(Wb + 0);
        wc[1] = *(const floatx4*)(Wb + 4);
        wc[2] = *(const floatx4*)(Wb + 8);
        wc[3] = *(const floatx4*)(Wb + 12);
        hcx = vt[vrow * 3 + 0]; hcy = vt[vrow * 3 + 1]; hcz = vt[vrow * 3 + 2];
    }

    WAITVM0();
    __syncthreads();    // B slab resident; read-only hereafter

    for (int t = 0; t < ntiles; ++t) {
        float* ecur = (t & 1) ? epi1 : epi0;

        // ---- deferred store of tile t-1 (other buffer): its LDS data was
        //      written last iteration; stores drain under THIS tile's MFMA.
        if (t > 0) do_store(t - 1, (t & 1) ? epi0 : epi1);

        // ---- issue prefetch for tile t+1 (latency hidden under MFMA)
        floatx4 wn[4]; float hnx = 0.f, hny = 0.f, hnz = 0.f;
        if (t + 1 < ntiles) {
            int vr = (start + t + 1) * 16 + lrow;
            if (vr > NV - 1) vr = NV - 1;
            const float* Wb = W + (size_t)vr * NJ + lk * 16;
            wn[0] = *(const floatx4*)(Wb + 0);
            wn[1] = *(const floatx4*)(Wb + 4);
            wn[2] = *(const floatx4*)(Wb + 8);
            wn[3] = *(const floatx4*)(Wb + 12);
            hnx = vt[vr * 3 + 0]; hny = vt[vr * 3 + 1]; hnz = vt[vr * 3 + 2];
        } else {
            wn[0] = wn[1] = wn[2] = wn[3] = (floatx4){0.f, 0.f, 0.f, 0.f};
        }

        // ---- MFMA: A frag built inline per k8 from contiguous weights;
        //      B frags from LDS (swizzled ds_read_b128).
        floatx4 acc[3];
        #pragma unroll
        for (int nt = 0; nt < 3; ++nt) acc[nt] = (floatx4){0.f, 0.f, 0.f, 0.f};
        __builtin_amdgcn_s_setprio(1);
        #pragma unroll
        for (int k8 = 0; k8 < 8; ++k8) {
            // joints 16*lk + 2*k8, +1  ->  wc[k8/2][2*(k8%2)], [..+1]
            float w0 = wc[k8 >> 1][2 * (k8 & 1)];
            float w1 = wc[k8 >> 1][2 * (k8 & 1) + 1];
            if (lk == 3 && k8 == 7) { w0 = 0.f; w1 = 0.f; }   // joints 62,63
            const short8v a = pack8(w0 * hcx, w0 * hcy, w0 * hcz, w0,
                                    w1 * hcx, w1 * hcy, w1 * hcz, w1);
            const unsigned cb = (unsigned)(k8 * 4 + lk) * 16;
            #pragma unroll
            for (int nt = 0; nt < 3; ++nt) {
                const short8v bf = *(const short8v*)(ldsB + bofs[nt] + (cb ^ bxor[nt]));
                acc[nt] = __builtin_amdgcn_mfma_f32_16x16x32_bf16(
                    a, bf, acc[nt], 0, 0, 0);
            }
        }
        __builtin_amdgcn_s_setprio(0);

        // ---- epilogue transpose into current buffer (stored next iter)
        #pragma unroll
        for (int nt = 0; nt < 3; ++nt) {
            #pragma unroll
            for (int r = 0; r < 4; ++r)
                ecur[eoff[nt] + (lk * 4 + r) * 3] =
                    fmaf(acc[nt][r], sv[nt], tv[nt]);
        }

        // ---- rotate prefetch
        wc[0] = wn[0]; wc[1] = wn[1]; wc[2] = wn[2]; wc[3] = wn[3];
        hcx = hnx; hcy = hny; hcz = hnz;
    }

    // ---- epilogue: flush the final tile
    do_store(ntiles - 1, ((ntiles - 1) & 1) ? epi1 : epi0);
}

extern "C" void kernel_launch(void* const* d_in, const int* in_sizes, int n_in,
                              void* d_out, int out_size, void* d_ws, size_t ws_size,
                              hipStream_t stream)
{
    const float* thetas  = (const float*)d_in[0];
    const float* blc     = (const float*)d_in[1];
    const float* cbl     = (const float*)d_in[2];
    const float* trans   = (const float*)d_in[3];
    const float* scale   = (const float*)d_in[4];
    const float* vtempl  = (const float*)d_in[5];
    const float* tpose   = (const float*)d_in[6];
    const float* weights = (const float*)d_in[7];
    const int*   parents = (const int*)d_in[8];
    const int*   mapper  = (const int*)d_in[9];

    float* out  = (float*)d_out;
    float* Jout = out + (size_t)256 * NV * 3;

    short* Bt = (short*)d_ws;                    // 768*KPAD bf16 = 0.39 MB

    fk_kernel<<<64, 256, 0, stream>>>(thetas, blc, cbl, trans, scale, tpose,
                                      parents, mapper, Bt, Jout);
    gemm_skin<<<768, 256, 0, stream>>>(weights, vtempl, Bt, scale, trans, out);
}